// Round 5
// baseline (21696.732 us; speedup 1.0000x reference)
//
#include <hip/hip_runtime.h>

#define T_STEPS 24000
#define DIN 598
#define NU 100      // hidden units
#define NG 400      // 4 * NU gates
#define KHALF 52    // k-slice per thread (2 x 52 = 104 = padded K)
#define KPAD 104
#define CHUNK 240   // steps per pipeline chunk
#define NCHUNK 100
#define RING 4      // ring capacity in chunks
#define RN (RING * CHUNK)   // 960 ring rows

typedef float v2f __attribute__((ext_vector_type(2)));
typedef float v4f __attribute__((ext_vector_type(4)));

// LDS-only barrier: orders ds ops without draining global loads/stores.
#define BARRIER_LDS() asm volatile("s_waitcnt lgkmcnt(0)\n\ts_barrier" ::: "memory")

// Pin a loaded value against rematerialization.
#define PIN_V2(x) asm volatile("" : "+v"(x))

// Packed FMA with hardware operand broadcast (R16).
// acc(2xf32) += w(2xf32) * broadcast(h.lo or h.hi).
// op_sel list is [src0,src1,src2]; op_sel   bit = which half feeds LO result,
//                                 op_sel_hi bit = which half feeds HI result.
// LO-broadcast of src1: op_sel[1]=0, op_sel_hi[1]=0 -> [0,0,0]/[1,0,1]
// HI-broadcast of src1: op_sel[1]=1, op_sel_hi[1]=1 -> [0,1,0]/[1,1,1]
// "v" constraints force VGPR (not AGPR) residency for weights and acc.
#define PKFMA_LO(acc, w, hp) \
    asm("v_pk_fma_f32 %0, %1, %2, %0 op_sel:[0,0,0] op_sel_hi:[1,0,1]" \
        : "+v"(acc) : "v"(w), "v"(hp))
#define PKFMA_HI(acc, w, hp) \
    asm("v_pk_fma_f32 %0, %1, %2, %0 op_sel:[0,1,0] op_sel_hi:[1,1,1]" \
        : "+v"(acc) : "v"(w), "v"(hp))

// Quad-perm DPP lane-pair add: x + x_from(lane^1).  Pure VALU (no LDS pipe),
// bit-exact replacement for x + __shfl_xor(x, 1) when both lanes are active.
__device__ __forceinline__ float dpp_add_x1(float x) {
    int y = __builtin_amdgcn_mov_dpp(__float_as_int(x), 0xB1, 0xF, 0xF, true);
    return x + __int_as_float(y);
}

// ---------------------------------------------------------------------------
// cross-WG sync helpers (device-scope; per-XCD L2s are non-coherent)
// ---------------------------------------------------------------------------
__device__ __forceinline__ void wg_wait_ge(int* flag, int target) {
    if (threadIdx.x == 0) {
        while (__hip_atomic_load(flag, __ATOMIC_RELAXED, __HIP_MEMORY_SCOPE_AGENT) < target)
            __builtin_amdgcn_s_sleep(2);
    }
    __syncthreads();
    __builtin_amdgcn_fence(__ATOMIC_ACQUIRE, "agent");
}
__device__ __forceinline__ void wg_publish(int* a, int va, int* b, int vb) {
    __syncthreads();
    if (threadIdx.x == 0) {
        if (a) __hip_atomic_store(a, va, __ATOMIC_RELEASE, __HIP_MEMORY_SCOPE_AGENT);
        if (b) __hip_atomic_store(b, vb, __ATOMIC_RELEASE, __HIP_MEMORY_SCOPE_AGENT);
    }
}

// ---------------------------------------------------------------------------
__device__ __forceinline__ float sigmoid_(float x) {
    return 1.f / (1.f + __expf(-x));
}
__device__ __forceinline__ float tanh_(float x) {
    float e = __expf(2.f * x);
    return 1.f - 2.f / (e + 1.f);
}

// ---------------------------------------------------------------------------
// GEMM with bias: C[M,N] = A[M,K] @ B[K,N] + bias[N]   (fp32, 64x64 tile)
// Writes PERMUTED columns: col n=(g*100+u) lands at u*4+g (unit-major i,f,g,o).
// ---------------------------------------------------------------------------
__global__ __launch_bounds__(256) void gemm_bias_kernel(
    const float* __restrict__ A, const float* __restrict__ B,
    const float* __restrict__ bias, float* __restrict__ C,
    int M, int N, int K)
{
    __shared__ float As[16][65];
    __shared__ float Bs[16][65];
    const int tid = threadIdx.x;
    const int tx = tid & 15;
    const int ty = tid >> 4;
    const int bm = blockIdx.y * 64;
    const int bn = blockIdx.x * 64;
    float acc[4][4] = {};

    for (int k0 = 0; k0 < K; k0 += 16) {
        #pragma unroll
        for (int p = 0; p < 4; ++p) {
            int e = tid + p * 256;
            int r = e >> 4, cc = e & 15;
            int m = bm + r, k = k0 + cc;
            float v = (m < M && k < K) ? A[(long)m * K + k] : 0.f;
            As[cc][r] = v;
        }
        #pragma unroll
        for (int p = 0; p < 4; ++p) {
            int e = tid + p * 256;
            int r = e >> 6, cc = e & 63;
            int k = k0 + r, n = bn + cc;
            float v = (k < K && n < N) ? B[(long)k * N + n] : 0.f;
            Bs[r][cc] = v;
        }
        __syncthreads();
        #pragma unroll
        for (int kk = 0; kk < 16; ++kk) {
            float a[4], b[4];
            #pragma unroll
            for (int i = 0; i < 4; ++i) a[i] = As[kk][ty * 4 + i];
            #pragma unroll
            for (int j = 0; j < 4; ++j) b[j] = Bs[kk][tx * 4 + j];
            #pragma unroll
            for (int i = 0; i < 4; ++i)
                #pragma unroll
                for (int j = 0; j < 4; ++j)
                    acc[i][j] += a[i] * b[j];
        }
        __syncthreads();
    }
    #pragma unroll
    for (int i = 0; i < 4; ++i) {
        int m = bm + ty * 4 + i;
        if (m >= M) continue;
        #pragma unroll
        for (int j = 0; j < 4; ++j) {
            int n = bn + tx * 4 + j;
            if (n < N) {
                int pn = (n % 100) * 4 + (n / 100);   // unit-major permute
                C[(long)m * N + pn] = acc[i][j] + bias[n];
            }
        }
    }
}

// ---------------------------------------------------------------------------
// Recurrent role (R16 = R15 - staging + op_sel-broadcast asm pk_fma).
// R15 post-mortem: VALUBusy implied ~420 VALU instr/wave/step vs ~170
// structural.  Two compiler taxes: (1) VGPR_Count 152 < 208 weight regs ->
// overflow lived in AGPRs, one v_accvgpr_read per use (~104/step);
// (2) the {h,h} broadcast operand of pk_fma materialized as 2 v_movs per
// pair (~104/step).  Fix: inline-asm v_pk_fma_f32 with op_sel selecting the
// lo/hi half of an h register PAIR for both output halves (no movs), and
// "v" constraints pinning all weights into arch VGPRs (no AGPR shuttles).
// hbuf staging dropped (R15 showed it neutral) to keep pressure <= 256.
// FMA order per accumulator unchanged -> bit-exact (absmax 0.0).
// Layout: 256 thr / 4 waves; thread 2u+s owns unit u's 4 gates over k-half s.
// ---------------------------------------------------------------------------
__device__ void rec_role(
    const float* __restrict__ xz, int xz_ring,   // [T][400] or ring, permuted
    const float* __restrict__ U,                 // [100][400] original layout
    float* __restrict__ hout, long h_stride, int h_ring, // transposed [100][h_stride]
    int* flag_up, int* done_self, int* done_down, int* flag_self,
    float* lds)                                   // >= 2*KPAD floats
{
    float* hb0 = lds;            // 104 floats (pad zeros)
    float* hb1 = lds + KPAD;     // 416 B offset, 16B-aligned
    const int tid = threadIdx.x;
    const bool active = tid < 2 * NU;   // 200 workers
    const int u = tid >> 1;
    const int s = tid & 1;

    // weight pairs: uf01[i] = U[k][{0,100}+u], uf23[i] = U[k][{200,300}+u]
    v2f uf01[KHALF], uf23[KHALF];
    if (active) {
        const int k0 = KHALF * s;
        #pragma unroll
        for (int i = 0; i < KHALF; ++i) {
            int k = k0 + i;
            if (k < NU) {
                uf01[i] = (v2f){U[(long)k * NG + u],          U[(long)k * NG + NU + u]};
                uf23[i] = (v2f){U[(long)k * NG + 2 * NU + u], U[(long)k * NG + 3 * NU + u]};
            } else {
                uf01[i] = (v2f){0.f, 0.f};
                uf23[i] = (v2f){0.f, 0.f};
            }
            PIN_V2(uf01[i]); PIN_V2(uf23[i]);
        }
    }
    if (tid < KPAD) { hb0[tid] = 0.f; hb1[tid] = 0.f; }
    float c_state = 0.f;
    // 4-deep xw register pipeline: xwp0 used this step, xwp3 in flight (t+4)
    float2 xwp0 = make_float2(0.f, 0.f), xwp1 = xwp0, xwp2 = xwp0, xwp3 = xwp0;
    float4 hbatch = make_float4(0.f, 0.f, 0.f, 0.f);

    // incremental addressing state (no per-step %RN / 64-bit muls)
    const float* xz_lane = xz + 4 * u + 2 * s;    // per-lane column base
    float* hout_u = hout + (long)u * h_stride;    // per-lane row base
    int nxt  = 4 * NG;                            // element offset of row t+4
    int hoff = 0;                                 // store offset (t-3 wrapped)
    __syncthreads();

    auto step = [&](const float* hrd, float* hwr, int t) {
        if (active) {
            const v4f* h4 = (const v4f*)(hrd + KHALF * s);
            // rotate xw pipeline and issue the t+4 prefetch early
            float2 xw_use = xwp0;
            xwp0 = xwp1; xwp1 = xwp2; xwp2 = xwp3;
            if (t + 4 < T_STEPS) {
                xwp3 = *(const float2*)(xz_lane + nxt);
            }
            nxt += NG;
            if (xz_ring && nxt == RN * NG) nxt = 0;
            // FMA chain: loads interleave with asm pk_fma; op_sel broadcasts
            // h.lo/h.hi directly from the loaded pair (no duplication movs).
            v2f a01 = (v2f){0.f, 0.f};
            v2f a23 = (v2f){0.f, 0.f};
            #pragma unroll
            for (int q = 0; q < 13; ++q) {
                v4f hv = h4[q];
                v2f p01 = hv.xy;
                v2f p23 = hv.zw;
                PKFMA_LO(a01, uf01[4 * q + 0], p01);   // k = 4q+0
                PKFMA_LO(a23, uf23[4 * q + 0], p01);
                PKFMA_HI(a01, uf01[4 * q + 1], p01);   // k = 4q+1
                PKFMA_HI(a23, uf23[4 * q + 1], p01);
                PKFMA_LO(a01, uf01[4 * q + 2], p23);   // k = 4q+2
                PKFMA_LO(a23, uf23[4 * q + 2], p23);
                PKFMA_HI(a01, uf01[4 * q + 3], p23);   // k = 4q+3
                PKFMA_HI(a23, uf23[4 * q + 3], p23);
            }
            float ax = a01.x, ay = a01.y, az = a23.x, aw = a23.y;
            // fold this thread's xw pair: s=0 -> (i,f), s=1 -> (g,o)
            if (s == 0) { ax += xw_use.x; ay += xw_use.y; }
            else        { az += xw_use.x; aw += xw_use.y; }
            // combine k-halves with in-wave partner (lane^1) — DPP, no LDS
            ax = dpp_add_x1(ax);
            ay = dpp_add_x1(ay);
            az = dpp_add_x1(az);
            aw = dpp_add_x1(aw);
            float iv = sigmoid_(ax);
            float fv = sigmoid_(ay);
            float gv = tanh_(az);
            float ov = sigmoid_(aw);
            c_state = fv * c_state + iv * gv;    // replicated per pair
            float h = ov * tanh_(c_state);
            if (s == 0) {
                hwr[u] = h;                       // pad [100..103] stays 0
                // batch 4 steps of h, flush with one dwordx4 (t%4==3)
                int ph = t & 3;
                if      (ph == 0) hbatch.x = h;
                else if (ph == 1) hbatch.y = h;
                else if (ph == 2) hbatch.z = h;
                else {
                    hbatch.w = h;
                    *(float4*)(hout_u + hoff) = hbatch;
                    hoff += 4;
                    if (h_ring && hoff == RN) hoff = 0;
                }
            }
        }
        BARRIER_LDS();
    };

    for (int c = 0; c < NCHUNK; ++c) {
        if (flag_up) {
            int tgt = c + 2; if (tgt > NCHUNK) tgt = NCHUNK;
            wg_wait_ge(flag_up, tgt);
        }
        if (done_down && c >= RING) wg_wait_ge(done_down, c - RING + 1);
        if (c == 0 && active) {
            xwp0 = *(const float2*)(xz_lane);
            xwp1 = *(const float2*)(xz_lane + NG);
            xwp2 = *(const float2*)(xz_lane + 2 * NG);
            xwp3 = *(const float2*)(xz_lane + 3 * NG);
        }
        const int t0 = c * CHUNK;
        for (int tt = 0; tt < CHUNK; tt += 2) {
            step(hb0, hb1, t0 + tt);
            step(hb1, hb0, t0 + tt + 1);
        }
        wg_publish(done_self, c + 1, flag_self, c + 1);   // vmcnt(0) drained inside
    }
}

// ---------------------------------------------------------------------------
// Projection role (R16: op_sel-broadcast asm pk_fma, same as rec_role).
// Reads TRANSPOSED h ring hin[u][RN]; staging loop iterates t-major so
// global reads stay coalesced.
// ---------------------------------------------------------------------------
__device__ void proj_role(
    const float* __restrict__ hin,     // transposed ring [100][RN]
    const float* __restrict__ W,       // [100][400] original layout
    const float* __restrict__ bias,    // [400] gate-major index
    const float* __restrict__ g, const float* __restrict__ be,
    const float* __restrict__ m, const float* __restrict__ v,
    float* __restrict__ xzout,         // ring [RN][400] permuted
    int* flag_up, int* done_self, int* done_down, int* flag_self,
    float* lds)                         // CHUNK*KPAD floats (99.8 KB)
{
    const int tid = threadIdx.x;
    const bool active = tid < 2 * NU;
    const int u = tid >> 1;
    const int s = tid & 1;

    v2f wf01[KHALF], wf23[KHALF];
    float bx = 0.f, by = 0.f;
    if (active) {
        const int k0 = KHALF * s;
        float pbx = 0.f, pby = 0.f, pbz = 0.f, pbw = 0.f;
        #pragma unroll
        for (int i = 0; i < KHALF; ++i) {
            int k = k0 + i;
            if (k < NU) {
                float sc = g[k] * rsqrtf(v[k] + 1e-3f);
                float sh = be[k] - m[k] * sc;
                float w0 = W[(long)k * NG + u];
                float w1 = W[(long)k * NG + NU + u];
                float w2 = W[(long)k * NG + 2 * NU + u];
                float w3 = W[(long)k * NG + 3 * NU + u];
                wf01[i] = (v2f){sc * w0, sc * w1};
                wf23[i] = (v2f){sc * w2, sc * w3};
                pbx += sh * w0; pby += sh * w1; pbz += sh * w2; pbw += sh * w3;
            } else {
                wf01[i] = (v2f){0.f, 0.f};
                wf23[i] = (v2f){0.f, 0.f};
            }
            PIN_V2(wf01[i]); PIN_V2(wf23[i]);
        }
        pbx += __shfl_xor(pbx, 1); pby += __shfl_xor(pby, 1);
        pbz += __shfl_xor(pbz, 1); pbw += __shfl_xor(pbw, 1);
        if (s == 0) { bx = bias[u]          + pbx; by = bias[NU + u]     + pby; }
        else        { bx = bias[2 * NU + u] + pbz; by = bias[3 * NU + u] + pbw; }
    }

    for (int c = 0; c < NCHUNK; ++c) {
        wg_wait_ge(flag_up, c + 1);
        if (c >= RING) wg_wait_ge(done_down, c - RING + 1);
        // stage h chunk into LDS[r][k] (row stride KPAD, zeros in pad).
        // t-major iteration: consecutive tid -> consecutive t (coalesced).
        {
            const int tbase = (c % RING) * CHUNK;   // == t0 % RN
            for (int idx = tid; idx < KPAD * CHUNK; idx += 256) {
                int k = idx / CHUNK, r = idx - k * CHUNK;
                lds[r * KPAD + k] = (k < NU) ? hin[(long)k * RN + tbase + r] : 0.f;
            }
        }
        wg_publish(done_self, c + 1, (int*)0, 0);
        if (active) {
            float* ob = xzout + (size_t)(c % RING) * CHUNK * NG;
            for (int r = 0; r < CHUNK; ++r) {
                const v4f* h4 = (const v4f*)(lds + r * KPAD + KHALF * s);
                v2f a01 = (v2f){0.f, 0.f};
                v2f a23 = (v2f){0.f, 0.f};
                #pragma unroll
                for (int q = 0; q < 13; ++q) {
                    v4f hv = h4[q];
                    v2f p01 = hv.xy;
                    v2f p23 = hv.zw;
                    PKFMA_LO(a01, wf01[4 * q + 0], p01);
                    PKFMA_LO(a23, wf23[4 * q + 0], p01);
                    PKFMA_HI(a01, wf01[4 * q + 1], p01);
                    PKFMA_HI(a23, wf23[4 * q + 1], p01);
                    PKFMA_LO(a01, wf01[4 * q + 2], p23);
                    PKFMA_LO(a23, wf23[4 * q + 2], p23);
                    PKFMA_HI(a01, wf01[4 * q + 3], p23);
                    PKFMA_HI(a23, wf23[4 * q + 3], p23);
                }
                float ax = a01.x, ay = a01.y, az = a23.x, aw = a23.y;
                ax = dpp_add_x1(ax);
                ay = dpp_add_x1(ay);
                az = dpp_add_x1(az);
                aw = dpp_add_x1(aw);
                float2 o2 = (s == 0) ? make_float2(ax + bx, ay + by)
                                     : make_float2(az + bx, aw + by);
                *(float2*)&ob[(long)r * NG + 4 * u + 2 * s] = o2;
            }
        }
        wg_publish(flag_self, c + 1, (int*)0, 0);
    }
}

// ---------------------------------------------------------------------------
// Persistent pipeline: block 0..4 = rec1, proj2, rec2, proj3, rec3.
// waves_per_eu(1,1): one 4-wave block per CU -> full per-wave register
// budget so the 208 weight VGPRs stay arch-VGPR resident (no AGPR copies).
// ---------------------------------------------------------------------------
__global__ __launch_bounds__(256)
__attribute__((amdgpu_waves_per_eu(1, 1)))
void lstm_pipe_kernel(
    const float* xw1, const float* U1,
    const float* U2, const float* W2, const float* b2,
    const float* U3, const float* W3, const float* b3,
    const float* g1, const float* be1, const float* m1, const float* v1,
    const float* g2, const float* be2, const float* m2, const float* v2,
    float* h1r, float* h2r, float* xz2r, float* xz3r, float* h3,
    int* f)
{
    extern __shared__ float smem[];
    int* f_h1  = f +   0;
    int* d_p2  = f +  32;
    int* f_xz2 = f +  64;
    int* d_r2  = f +  96;
    int* f_h2  = f + 128;
    int* d_p3  = f + 160;
    int* f_xz3 = f + 192;
    int* d_r3  = f + 224;

    switch (blockIdx.x) {
    case 0: rec_role(xw1, 0, U1, h1r, RN, 1, (int*)0, (int*)0, d_p2, f_h1, smem); break;
    case 1: proj_role(h1r, W2, b2, g1, be1, m1, v1, xz2r, f_h1, d_p2, d_r2, f_xz2, smem); break;
    case 2: rec_role(xz2r, 1, U2, h2r, RN, 1, f_xz2, d_r2, d_p3, f_h2, smem); break;
    case 3: proj_role(h2r, W3, b3, g2, be2, m2, v2, xz3r, f_h2, d_p3, d_r3, f_xz3, smem); break;
    case 4: rec_role(xz3r, 1, U3, h3, T_STEPS, 0, f_xz3, d_r3, (int*)0, (int*)0, smem); break;
    }
}

// ---------------------------------------------------------------------------
// Dense (100->3) + softmax, BN3 folded.  H is TRANSPOSED [100][T] -> the
// per-k read h[k*T+row] is perfectly coalesced across threads (rows).
// ---------------------------------------------------------------------------
__global__ __launch_bounds__(256) void dense_softmax_kernel(
    const float* __restrict__ H,    // [100][T] raw h3 (transposed)
    const float* __restrict__ Wd,
    const float* __restrict__ bd,
    const float* __restrict__ g3, const float* __restrict__ be3,
    const float* __restrict__ m3, const float* __restrict__ v3,
    float* __restrict__ out, int T)
{
    __shared__ float w[300];
    __shared__ float b[3];
    const int tid = threadIdx.x;
    for (int i = tid; i < 300; i += 256) {
        int k = i / 3;
        float sc = g3[k] * rsqrtf(v3[k] + 1e-3f);
        w[i] = Wd[i] * sc;
    }
    if (tid < 3) {
        float acc = bd[tid];
        for (int k = 0; k < NU; ++k) {
            float sc = g3[k] * rsqrtf(v3[k] + 1e-3f);
            float sh = be3[k] - m3[k] * sc;
            acc += sh * Wd[3 * k + tid];
        }
        b[tid] = acc;
    }
    __syncthreads();

    int row = blockIdx.x * blockDim.x + tid;
    if (row >= T) return;
    float s0 = b[0], s1 = b[1], s2 = b[2];
    #pragma unroll 4
    for (int k = 0; k < NU; ++k) {
        float hv = H[(long)k * T + row];
        s0 += hv * w[3 * k + 0];
        s1 += hv * w[3 * k + 1];
        s2 += hv * w[3 * k + 2];
    }
    float mx = fmaxf(s0, fmaxf(s1, s2));
    float e0 = __expf(s0 - mx), e1 = __expf(s1 - mx), e2 = __expf(s2 - mx);
    float inv = 1.f / (e0 + e1 + e2);
    out[(long)row * 3 + 0] = e0 * inv;
    out[(long)row * 3 + 1] = e1 * inv;
    out[(long)row * 3 + 2] = e2 * inv;
}

// ---------------------------------------------------------------------------
extern "C" void kernel_launch(void* const* d_in, const int* in_sizes, int n_in,
                              void* d_out, int out_size, void* d_ws, size_t ws_size,
                              hipStream_t stream)
{
    const float* x   = (const float*)d_in[0];
    const float* W1  = (const float*)d_in[1];
    const float* U1  = (const float*)d_in[2];
    const float* b1  = (const float*)d_in[3];
    const float* ga1 = (const float*)d_in[4];
    const float* be1 = (const float*)d_in[5];
    const float* mu1 = (const float*)d_in[6];
    const float* va1 = (const float*)d_in[7];
    const float* W2  = (const float*)d_in[8];
    const float* U2  = (const float*)d_in[9];
    const float* b2  = (const float*)d_in[10];
    const float* ga2 = (const float*)d_in[11];
    const float* be2 = (const float*)d_in[12];
    const float* mu2 = (const float*)d_in[13];
    const float* va2 = (const float*)d_in[14];
    const float* W3  = (const float*)d_in[15];
    const float* U3  = (const float*)d_in[16];
    const float* b3  = (const float*)d_in[17];
    const float* ga3 = (const float*)d_in[18];
    const float* be3 = (const float*)d_in[19];
    const float* mu3 = (const float*)d_in[20];
    const float* va3 = (const float*)d_in[21];
    const float* Wd  = (const float*)d_in[22];
    const float* bd  = (const float*)d_in[23];

    // workspace layout (floats) — total ~51.9 MB
    float* xw1  = (float*)d_ws;                       // T*400 (permuted)
    float* h3   = xw1  + (size_t)T_STEPS * NG;        // [100][T] transposed
    float* h1r  = h3   + (size_t)T_STEPS * NU;        // [100][RN] transposed ring
    float* h2r  = h1r  + (size_t)RN * NU;
    float* xz2r = h2r  + (size_t)RN * NU;             // RN*400 (permuted)
    float* xz3r = xz2r + (size_t)RN * NG;
    int*   flags = (int*)(xz3r + (size_t)RN * NG);    // 512 ints
    float* out = (float*)d_out;

    dim3 blk(256);
    dim3 grd((NG + 63) / 64, (T_STEPS + 63) / 64);

    // 1) input projection of layer 1 (permuted-column output)
    gemm_bias_kernel<<<grd, blk, 0, stream>>>(x, W1, b1, xw1, T_STEPS, NG, DIN);
    // 2) zero the pipeline flags
    hipMemsetAsync(flags, 0, 512 * sizeof(int), stream);
    // 3) persistent pipeline: 5 blocks x 256 threads, 99.8 KB dynamic LDS
    lstm_pipe_kernel<<<5, 256, CHUNK * KPAD * sizeof(float), stream>>>(
        xw1, U1, U2, W2, b2, U3, W3, b3,
        ga1, be1, mu1, va1, ga2, be2, mu2, va2,
        h1r, h2r, xz2r, xz3r, h3, flags);
    // 4) dense + softmax (BN3 folded, transposed-H reads)
    dense_softmax_kernel<<<(T_STEPS + 255) / 256, 256, 0, stream>>>(
        h3, Wd, bd, ga3, be3, mu3, va3, out, T_STEPS);
}

// Round 6
// 21066.907 us; speedup vs baseline: 1.0299x; 1.0299x over previous
//
#include <hip/hip_runtime.h>

#define T_STEPS 24000
#define DIN 598
#define NU 100      // hidden units
#define NG 400      // 4 * NU gates
#define KHALF 52    // k-slice per thread (2 x 52 = 104 = padded K)
#define KPAIR 26    // k-pairs per thread per gate
#define KPAD 104
#define CHUNK 240   // steps per pipeline chunk
#define NCHUNK 100
#define RING 4      // ring capacity in chunks
#define RN (RING * CHUNK)   // 960 ring rows

typedef float v2f __attribute__((ext_vector_type(2)));
typedef float v4f __attribute__((ext_vector_type(4)));

// LDS-only barrier: orders ds ops without draining global loads/stores.
#define BARRIER_LDS() asm volatile("s_waitcnt lgkmcnt(0)\n\ts_barrier" ::: "memory")

// Pin a loaded value against rematerialization.
#define PIN_V2(x) asm volatile("" : "+v"(x))

// Quad-perm DPP lane-pair add: x + x_from(lane^1).  Pure VALU (no LDS pipe),
// bit-exact replacement for x + __shfl_xor(x, 1) when both lanes are active.
__device__ __forceinline__ float dpp_add_x1(float x) {
    int y = __builtin_amdgcn_mov_dpp(__float_as_int(x), 0xB1, 0xF, 0xF, true);
    return x + __int_as_float(y);
}

// ---------------------------------------------------------------------------
// cross-WG sync helpers (device-scope; per-XCD L2s are non-coherent)
// ---------------------------------------------------------------------------
__device__ __forceinline__ void wg_wait_ge(int* flag, int target) {
    if (threadIdx.x == 0) {
        while (__hip_atomic_load(flag, __ATOMIC_RELAXED, __HIP_MEMORY_SCOPE_AGENT) < target)
            __builtin_amdgcn_s_sleep(2);
    }
    __syncthreads();
    __builtin_amdgcn_fence(__ATOMIC_ACQUIRE, "agent");
}
__device__ __forceinline__ void wg_publish(int* a, int va, int* b, int vb) {
    __syncthreads();
    if (threadIdx.x == 0) {
        if (a) __hip_atomic_store(a, va, __ATOMIC_RELEASE, __HIP_MEMORY_SCOPE_AGENT);
        if (b) __hip_atomic_store(b, vb, __ATOMIC_RELEASE, __HIP_MEMORY_SCOPE_AGENT);
    }
}

// ---------------------------------------------------------------------------
__device__ __forceinline__ float sigmoid_(float x) {
    return 1.f / (1.f + __expf(-x));
}
__device__ __forceinline__ float tanh_(float x) {
    float e = __expf(2.f * x);
    return 1.f - 2.f / (e + 1.f);
}

// ---------------------------------------------------------------------------
// GEMM with bias: C[M,N] = A[M,K] @ B[K,N] + bias[N]   (fp32, 64x64 tile)
// Writes PERMUTED columns: col n=(g*100+u) lands at u*4+g (unit-major i,f,g,o).
// ---------------------------------------------------------------------------
__global__ __launch_bounds__(256) void gemm_bias_kernel(
    const float* __restrict__ A, const float* __restrict__ B,
    const float* __restrict__ bias, float* __restrict__ C,
    int M, int N, int K)
{
    __shared__ float As[16][65];
    __shared__ float Bs[16][65];
    const int tid = threadIdx.x;
    const int tx = tid & 15;
    const int ty = tid >> 4;
    const int bm = blockIdx.y * 64;
    const int bn = blockIdx.x * 64;
    float acc[4][4] = {};

    for (int k0 = 0; k0 < K; k0 += 16) {
        #pragma unroll
        for (int p = 0; p < 4; ++p) {
            int e = tid + p * 256;
            int r = e >> 4, cc = e & 15;
            int m = bm + r, k = k0 + cc;
            float v = (m < M && k < K) ? A[(long)m * K + k] : 0.f;
            As[cc][r] = v;
        }
        #pragma unroll
        for (int p = 0; p < 4; ++p) {
            int e = tid + p * 256;
            int r = e >> 6, cc = e & 63;
            int k = k0 + r, n = bn + cc;
            float v = (k < K && n < N) ? B[(long)k * N + n] : 0.f;
            Bs[r][cc] = v;
        }
        __syncthreads();
        #pragma unroll
        for (int kk = 0; kk < 16; ++kk) {
            float a[4], b[4];
            #pragma unroll
            for (int i = 0; i < 4; ++i) a[i] = As[kk][ty * 4 + i];
            #pragma unroll
            for (int j = 0; j < 4; ++j) b[j] = Bs[kk][tx * 4 + j];
            #pragma unroll
            for (int i = 0; i < 4; ++i)
                #pragma unroll
                for (int j = 0; j < 4; ++j)
                    acc[i][j] += a[i] * b[j];
        }
        __syncthreads();
    }
    #pragma unroll
    for (int i = 0; i < 4; ++i) {
        int m = bm + ty * 4 + i;
        if (m >= M) continue;
        #pragma unroll
        for (int j = 0; j < 4; ++j) {
            int n = bn + tx * 4 + j;
            if (n < N) {
                int pn = (n % 100) * 4 + (n / 100);   // unit-major permute
                C[(long)m * N + pn] = acc[i][j] + bias[n];
            }
        }
    }
}

// ---------------------------------------------------------------------------
// Recurrent role (R17 = R15 with k-pair packing, no splat movs).
// R15 counter forensics: VALUBusy ~= 830 busy-cyc/step = 416 instr x 2cyc =
// 104 v_pk_fma + 104 {h,h}-splat v_mov pairs.  Fix: pack along K instead of
// along gates -- per gate g, acc_g(v2f) += {w[k],w[k+1]} * {h[k],h[k+1]},
// where the h pair is hv.xy / hv.zw of the existing ds_read_b128 (a natural
// aligned VGPR pair, zero movs).  4 gate accumulators x 26 k-pairs = same
// 208 weight VGPRs.  Horizontal add acc.x+acc.y per gate at the end.
// NOTE: changes reduction association (even/odd split-k) -> absmax ~1e-6
// instead of bit-exact 0; well within tolerance.
// Layout: 256 thr / 4 waves; thread 2u+s owns unit u's 4 gates over k-half s.
// ---------------------------------------------------------------------------
__device__ void rec_role(
    const float* __restrict__ xz, int xz_ring,   // [T][400] or ring, permuted
    const float* __restrict__ U,                 // [100][400] original layout
    float* __restrict__ hout, long h_stride, int h_ring, // transposed [100][h_stride]
    int* flag_up, int* done_self, int* done_down, int* flag_self,
    float* lds)                                   // >= 2*KPAD floats
{
    float* hb0 = lds;            // 104 floats (pad zeros)
    float* hb1 = lds + KPAD;     // 416 B offset, 16B-aligned
    const int tid = threadIdx.x;
    const bool active = tid < 2 * NU;   // 200 workers
    const int u = tid >> 1;
    const int s = tid & 1;

    // per-gate k-pair weights: ug[g][j] = {U[k][g*100+u], U[k+1][g*100+u]},
    // k = KHALF*s + 2j; zeros for k >= 100.
    v2f u0[KPAIR], u1[KPAIR], u2[KPAIR], u3[KPAIR];
    if (active) {
        const int k0 = KHALF * s;
        #pragma unroll
        for (int j = 0; j < KPAIR; ++j) {
            int k = k0 + 2 * j;
            float a0 = 0.f, b0 = 0.f, a1 = 0.f, b1 = 0.f,
                  a2 = 0.f, b2 = 0.f, a3 = 0.f, b3 = 0.f;
            if (k < NU) {
                a0 = U[(long)k * NG + u];          a1 = U[(long)k * NG + NU + u];
                a2 = U[(long)k * NG + 2 * NU + u]; a3 = U[(long)k * NG + 3 * NU + u];
            }
            if (k + 1 < NU) {
                b0 = U[(long)(k + 1) * NG + u];          b1 = U[(long)(k + 1) * NG + NU + u];
                b2 = U[(long)(k + 1) * NG + 2 * NU + u]; b3 = U[(long)(k + 1) * NG + 3 * NU + u];
            }
            u0[j] = (v2f){a0, b0}; u1[j] = (v2f){a1, b1};
            u2[j] = (v2f){a2, b2}; u3[j] = (v2f){a3, b3};
            PIN_V2(u0[j]); PIN_V2(u1[j]); PIN_V2(u2[j]); PIN_V2(u3[j]);
        }
    }
    if (tid < KPAD) { hb0[tid] = 0.f; hb1[tid] = 0.f; }
    float c_state = 0.f;
    // 4-deep xw register pipeline: xwp0 used this step, xwp3 in flight (t+4)
    float2 xwp0 = make_float2(0.f, 0.f), xwp1 = xwp0, xwp2 = xwp0, xwp3 = xwp0;
    float4 hbatch = make_float4(0.f, 0.f, 0.f, 0.f);

    // incremental addressing state (no per-step %RN / 64-bit muls)
    const float* xz_lane = xz + 4 * u + 2 * s;    // per-lane column base
    float* hout_u = hout + (long)u * h_stride;    // per-lane row base
    int nxt  = 4 * NG;                            // element offset of row t+4
    int hoff = 0;                                 // store offset (t-3 wrapped)
    __syncthreads();

    auto step = [&](const float* hrd, float* hwr, int t) {
        if (active) {
            const v4f* h4 = (const v4f*)(hrd + KHALF * s);
            // rotate xw pipeline and issue the t+4 prefetch early
            float2 xw_use = xwp0;
            xwp0 = xwp1; xwp1 = xwp2; xwp2 = xwp3;
            if (t + 4 < T_STEPS) {
                xwp3 = *(const float2*)(xz_lane + nxt);
            }
            nxt += NG;
            if (xz_ring && nxt == RN * NG) nxt = 0;
            // k-pair packed FMA: h pairs come straight from the b128 load.
            v2f a0 = (v2f){0.f, 0.f}, a1 = (v2f){0.f, 0.f};
            v2f a2 = (v2f){0.f, 0.f}, a3 = (v2f){0.f, 0.f};
            #pragma unroll
            for (int q = 0; q < 13; ++q) {
                v4f hv = h4[q];
                v2f plo = hv.xy;                  // {h[4q],   h[4q+1]}
                v2f phi = hv.zw;                  // {h[4q+2], h[4q+3]}
                a0 = __builtin_elementwise_fma(u0[2 * q],     plo, a0);
                a1 = __builtin_elementwise_fma(u1[2 * q],     plo, a1);
                a2 = __builtin_elementwise_fma(u2[2 * q],     plo, a2);
                a3 = __builtin_elementwise_fma(u3[2 * q],     plo, a3);
                a0 = __builtin_elementwise_fma(u0[2 * q + 1], phi, a0);
                a1 = __builtin_elementwise_fma(u1[2 * q + 1], phi, a1);
                a2 = __builtin_elementwise_fma(u2[2 * q + 1], phi, a2);
                a3 = __builtin_elementwise_fma(u3[2 * q + 1], phi, a3);
            }
            float ax = a0.x + a0.y;
            float ay = a1.x + a1.y;
            float az = a2.x + a2.y;
            float aw = a3.x + a3.y;
            // fold this thread's xw pair: s=0 -> (i,f), s=1 -> (g,o)
            if (s == 0) { ax += xw_use.x; ay += xw_use.y; }
            else        { az += xw_use.x; aw += xw_use.y; }
            // combine k-halves with in-wave partner (lane^1) — DPP, no LDS
            ax = dpp_add_x1(ax);
            ay = dpp_add_x1(ay);
            az = dpp_add_x1(az);
            aw = dpp_add_x1(aw);
            float iv = sigmoid_(ax);
            float fv = sigmoid_(ay);
            float gv = tanh_(az);
            float ov = sigmoid_(aw);
            c_state = fv * c_state + iv * gv;    // replicated per pair
            float h = ov * tanh_(c_state);
            if (s == 0) {
                hwr[u] = h;                       // pad [100..103] stays 0
                // batch 4 steps of h, flush with one dwordx4 (t%4==3)
                int ph = t & 3;
                if      (ph == 0) hbatch.x = h;
                else if (ph == 1) hbatch.y = h;
                else if (ph == 2) hbatch.z = h;
                else {
                    hbatch.w = h;
                    *(float4*)(hout_u + hoff) = hbatch;
                    hoff += 4;
                    if (h_ring && hoff == RN) hoff = 0;
                }
            }
        }
        BARRIER_LDS();
    };

    for (int c = 0; c < NCHUNK; ++c) {
        if (flag_up) {
            int tgt = c + 2; if (tgt > NCHUNK) tgt = NCHUNK;
            wg_wait_ge(flag_up, tgt);
        }
        if (done_down && c >= RING) wg_wait_ge(done_down, c - RING + 1);
        if (c == 0 && active) {
            xwp0 = *(const float2*)(xz_lane);
            xwp1 = *(const float2*)(xz_lane + NG);
            xwp2 = *(const float2*)(xz_lane + 2 * NG);
            xwp3 = *(const float2*)(xz_lane + 3 * NG);
        }
        const int t0 = c * CHUNK;
        for (int tt = 0; tt < CHUNK; tt += 2) {
            step(hb0, hb1, t0 + tt);
            step(hb1, hb0, t0 + tt + 1);
        }
        wg_publish(done_self, c + 1, flag_self, c + 1);   // vmcnt(0) drained inside
    }
}

// ---------------------------------------------------------------------------
// Projection role (R17: same k-pair packing).  Reads TRANSPOSED h ring
// hin[u][RN]; staging loop iterates t-major so global reads stay coalesced.
// ---------------------------------------------------------------------------
__device__ void proj_role(
    const float* __restrict__ hin,     // transposed ring [100][RN]
    const float* __restrict__ W,       // [100][400] original layout
    const float* __restrict__ bias,    // [400] gate-major index
    const float* __restrict__ g, const float* __restrict__ be,
    const float* __restrict__ m, const float* __restrict__ v,
    float* __restrict__ xzout,         // ring [RN][400] permuted
    int* flag_up, int* done_self, int* done_down, int* flag_self,
    float* lds)                         // CHUNK*KPAD floats (99.8 KB)
{
    const int tid = threadIdx.x;
    const bool active = tid < 2 * NU;
    const int u = tid >> 1;
    const int s = tid & 1;

    v2f w0[KPAIR], w1[KPAIR], w2[KPAIR], w3[KPAIR];
    float bx = 0.f, by = 0.f;
    if (active) {
        const int k0 = KHALF * s;
        float pbx = 0.f, pby = 0.f, pbz = 0.f, pbw = 0.f;
        #pragma unroll
        for (int j = 0; j < KPAIR; ++j) {
            int k = k0 + 2 * j;
            float a0 = 0.f, b0 = 0.f, a1 = 0.f, b1 = 0.f,
                  a2 = 0.f, b2 = 0.f, a3 = 0.f, b3 = 0.f;
            if (k < NU) {
                float sc = g[k] * rsqrtf(v[k] + 1e-3f);
                float sh = be[k] - m[k] * sc;
                float q0 = W[(long)k * NG + u];
                float q1 = W[(long)k * NG + NU + u];
                float q2 = W[(long)k * NG + 2 * NU + u];
                float q3 = W[(long)k * NG + 3 * NU + u];
                a0 = sc * q0; a1 = sc * q1; a2 = sc * q2; a3 = sc * q3;
                pbx += sh * q0; pby += sh * q1; pbz += sh * q2; pbw += sh * q3;
            }
            if (k + 1 < NU) {
                int kk = k + 1;
                float sc = g[kk] * rsqrtf(v[kk] + 1e-3f);
                float sh = be[kk] - m[kk] * sc;
                float q0 = W[(long)kk * NG + u];
                float q1 = W[(long)kk * NG + NU + u];
                float q2 = W[(long)kk * NG + 2 * NU + u];
                float q3 = W[(long)kk * NG + 3 * NU + u];
                b0 = sc * q0; b1 = sc * q1; b2 = sc * q2; b3 = sc * q3;
                pbx += sh * q0; pby += sh * q1; pbz += sh * q2; pbw += sh * q3;
            }
            w0[j] = (v2f){a0, b0}; w1[j] = (v2f){a1, b1};
            w2[j] = (v2f){a2, b2}; w3[j] = (v2f){a3, b3};
            PIN_V2(w0[j]); PIN_V2(w1[j]); PIN_V2(w2[j]); PIN_V2(w3[j]);
        }
        pbx += __shfl_xor(pbx, 1); pby += __shfl_xor(pby, 1);
        pbz += __shfl_xor(pbz, 1); pbw += __shfl_xor(pbw, 1);
        if (s == 0) { bx = bias[u]          + pbx; by = bias[NU + u]     + pby; }
        else        { bx = bias[2 * NU + u] + pbz; by = bias[3 * NU + u] + pbw; }
    }

    for (int c = 0; c < NCHUNK; ++c) {
        wg_wait_ge(flag_up, c + 1);
        if (c >= RING) wg_wait_ge(done_down, c - RING + 1);
        // stage h chunk into LDS[r][k] (row stride KPAD, zeros in pad).
        // t-major iteration: consecutive tid -> consecutive t (coalesced).
        {
            const int tbase = (c % RING) * CHUNK;   // == t0 % RN
            for (int idx = tid; idx < KPAD * CHUNK; idx += 256) {
                int k = idx / CHUNK, r = idx - k * CHUNK;
                lds[r * KPAD + k] = (k < NU) ? hin[(long)k * RN + tbase + r] : 0.f;
            }
        }
        wg_publish(done_self, c + 1, (int*)0, 0);
        if (active) {
            float* ob = xzout + (size_t)(c % RING) * CHUNK * NG;
            for (int r = 0; r < CHUNK; ++r) {
                const v4f* h4 = (const v4f*)(lds + r * KPAD + KHALF * s);
                v2f a0 = (v2f){0.f, 0.f}, a1 = (v2f){0.f, 0.f};
                v2f a2 = (v2f){0.f, 0.f}, a3 = (v2f){0.f, 0.f};
                #pragma unroll
                for (int q = 0; q < 13; ++q) {
                    v4f hv = h4[q];
                    v2f plo = hv.xy;
                    v2f phi = hv.zw;
                    a0 = __builtin_elementwise_fma(w0[2 * q],     plo, a0);
                    a1 = __builtin_elementwise_fma(w1[2 * q],     plo, a1);
                    a2 = __builtin_elementwise_fma(w2[2 * q],     plo, a2);
                    a3 = __builtin_elementwise_fma(w3[2 * q],     plo, a3);
                    a0 = __builtin_elementwise_fma(w0[2 * q + 1], phi, a0);
                    a1 = __builtin_elementwise_fma(w1[2 * q + 1], phi, a1);
                    a2 = __builtin_elementwise_fma(w2[2 * q + 1], phi, a2);
                    a3 = __builtin_elementwise_fma(w3[2 * q + 1], phi, a3);
                }
                float ax = a0.x + a0.y;
                float ay = a1.x + a1.y;
                float az = a2.x + a2.y;
                float aw = a3.x + a3.y;
                ax = dpp_add_x1(ax);
                ay = dpp_add_x1(ay);
                az = dpp_add_x1(az);
                aw = dpp_add_x1(aw);
                float2 o2 = (s == 0) ? make_float2(ax + bx, ay + by)
                                     : make_float2(az + bx, aw + by);
                *(float2*)&ob[(long)r * NG + 4 * u + 2 * s] = o2;
            }
        }
        wg_publish(flag_self, c + 1, (int*)0, 0);
    }
}

// ---------------------------------------------------------------------------
// Persistent pipeline: block 0..4 = rec1, proj2, rec2, proj3, rec3.
// waves_per_eu(1,1): one 4-wave block per CU -> full per-wave register
// budget for the 208-VGPR weight-resident layout.
// ---------------------------------------------------------------------------
__global__ __launch_bounds__(256)
__attribute__((amdgpu_waves_per_eu(1, 1)))
void lstm_pipe_kernel(
    const float* xw1, const float* U1,
    const float* U2, const float* W2, const float* b2,
    const float* U3, const float* W3, const float* b3,
    const float* g1, const float* be1, const float* m1, const float* v1,
    const float* g2, const float* be2, const float* m2, const float* v2,
    float* h1r, float* h2r, float* xz2r, float* xz3r, float* h3,
    int* f)
{
    extern __shared__ float smem[];
    int* f_h1  = f +   0;
    int* d_p2  = f +  32;
    int* f_xz2 = f +  64;
    int* d_r2  = f +  96;
    int* f_h2  = f + 128;
    int* d_p3  = f + 160;
    int* f_xz3 = f + 192;
    int* d_r3  = f + 224;

    switch (blockIdx.x) {
    case 0: rec_role(xw1, 0, U1, h1r, RN, 1, (int*)0, (int*)0, d_p2, f_h1, smem); break;
    case 1: proj_role(h1r, W2, b2, g1, be1, m1, v1, xz2r, f_h1, d_p2, d_r2, f_xz2, smem); break;
    case 2: rec_role(xz2r, 1, U2, h2r, RN, 1, f_xz2, d_r2, d_p3, f_h2, smem); break;
    case 3: proj_role(h2r, W3, b3, g2, be2, m2, v2, xz3r, f_h2, d_p3, d_r3, f_xz3, smem); break;
    case 4: rec_role(xz3r, 1, U3, h3, T_STEPS, 0, f_xz3, d_r3, (int*)0, (int*)0, smem); break;
    }
}

// ---------------------------------------------------------------------------
// Dense (100->3) + softmax, BN3 folded.  H is TRANSPOSED [100][T] -> the
// per-k read h[k*T+row] is perfectly coalesced across threads (rows).
// ---------------------------------------------------------------------------
__global__ __launch_bounds__(256) void dense_softmax_kernel(
    const float* __restrict__ H,    // [100][T] raw h3 (transposed)
    const float* __restrict__ Wd,
    const float* __restrict__ bd,
    const float* __restrict__ g3, const float* __restrict__ be3,
    const float* __restrict__ m3, const float* __restrict__ v3,
    float* __restrict__ out, int T)
{
    __shared__ float w[300];
    __shared__ float b[3];
    const int tid = threadIdx.x;
    for (int i = tid; i < 300; i += 256) {
        int k = i / 3;
        float sc = g3[k] * rsqrtf(v3[k] + 1e-3f);
        w[i] = Wd[i] * sc;
    }
    if (tid < 3) {
        float acc = bd[tid];
        for (int k = 0; k < NU; ++k) {
            float sc = g3[k] * rsqrtf(v3[k] + 1e-3f);
            float sh = be3[k] - m3[k] * sc;
            acc += sh * Wd[3 * k + tid];
        }
        b[tid] = acc;
    }
    __syncthreads();

    int row = blockIdx.x * blockDim.x + tid;
    if (row >= T) return;
    float s0 = b[0], s1 = b[1], s2 = b[2];
    #pragma unroll 4
    for (int k = 0; k < NU; ++k) {
        float hv = H[(long)k * T + row];
        s0 += hv * w[3 * k + 0];
        s1 += hv * w[3 * k + 1];
        s2 += hv * w[3 * k + 2];
    }
    float mx = fmaxf(s0, fmaxf(s1, s2));
    float e0 = __expf(s0 - mx), e1 = __expf(s1 - mx), e2 = __expf(s2 - mx);
    float inv = 1.f / (e0 + e1 + e2);
    out[(long)row * 3 + 0] = e0 * inv;
    out[(long)row * 3 + 1] = e1 * inv;
    out[(long)row * 3 + 2] = e2 * inv;
}

// ---------------------------------------------------------------------------
extern "C" void kernel_launch(void* const* d_in, const int* in_sizes, int n_in,
                              void* d_out, int out_size, void* d_ws, size_t ws_size,
                              hipStream_t stream)
{
    const float* x   = (const float*)d_in[0];
    const float* W1  = (const float*)d_in[1];
    const float* U1  = (const float*)d_in[2];
    const float* b1  = (const float*)d_in[3];
    const float* ga1 = (const float*)d_in[4];
    const float* be1 = (const float*)d_in[5];
    const float* mu1 = (const float*)d_in[6];
    const float* va1 = (const float*)d_in[7];
    const float* W2  = (const float*)d_in[8];
    const float* U2  = (const float*)d_in[9];
    const float* b2  = (const float*)d_in[10];
    const float* ga2 = (const float*)d_in[11];
    const float* be2 = (const float*)d_in[12];
    const float* mu2 = (const float*)d_in[13];
    const float* va2 = (const float*)d_in[14];
    const float* W3  = (const float*)d_in[15];
    const float* U3  = (const float*)d_in[16];
    const float* b3  = (const float*)d_in[17];
    const float* ga3 = (const float*)d_in[18];
    const float* be3 = (const float*)d_in[19];
    const float* mu3 = (const float*)d_in[20];
    const float* va3 = (const float*)d_in[21];
    const float* Wd  = (const float*)d_in[22];
    const float* bd  = (const float*)d_in[23];

    // workspace layout (floats) — total ~51.9 MB
    float* xw1  = (float*)d_ws;                       // T*400 (permuted)
    float* h3   = xw1  + (size_t)T_STEPS * NG;        // [100][T] transposed
    float* h1r  = h3   + (size_t)T_STEPS * NU;        // [100][RN] transposed ring
    float* h2r  = h1r  + (size_t)RN * NU;
    float* xz2r = h2r  + (size_t)RN * NU;             // RN*400 (permuted)
    float* xz3r = xz2r + (size_t)RN * NG;
    int*   flags = (int*)(xz3r + (size_t)RN * NG);    // 512 ints
    float* out = (float*)d_out;

    dim3 blk(256);
    dim3 grd((NG + 63) / 64, (T_STEPS + 63) / 64);

    // 1) input projection of layer 1 (permuted-column output)
    gemm_bias_kernel<<<grd, blk, 0, stream>>>(x, W1, b1, xw1, T_STEPS, NG, DIN);
    // 2) zero the pipeline flags
    hipMemsetAsync(flags, 0, 512 * sizeof(int), stream);
    // 3) persistent pipeline: 5 blocks x 256 threads, 99.8 KB dynamic LDS
    lstm_pipe_kernel<<<5, 256, CHUNK * KPAD * sizeof(float), stream>>>(
        xw1, U1, U2, W2, b2, U3, W3, b3,
        ga1, be1, mu1, va1, ga2, be2, mu2, va2,
        h1r, h2r, xz2r, xz3r, h3, flags);
    // 4) dense + softmax (BN3 folded, transposed-H reads)
    dense_softmax_kernel<<<(T_STEPS + 255) / 256, 256, 0, stream>>>(
        h3, Wd, bd, ga3, be3, mu3, va3, out, T_STEPS);
}

// Round 7
// 20431.552 us; speedup vs baseline: 1.0619x; 1.0311x over previous
//
#include <hip/hip_runtime.h>

#define T_STEPS 24000
#define DIN 598
#define NU 100      // hidden units
#define NG 400      // 4 * NU gates
#define KHALF 52    // k-slice per thread (2 x 52 = 104 = padded K)
#define KPAIR 26    // k-pairs per thread per gate
#define KPAD 104
#define CHUNK 240   // steps per pipeline chunk
#define NCHUNK 100
#define RING 4      // ring capacity in chunks
#define RN (RING * CHUNK)   // 960 ring rows
#define BLK 512     // R18: 8 waves, 2/SIMD; 400 workers (u, gate-pair, k-half)

typedef float v2f __attribute__((ext_vector_type(2)));
typedef float v4f __attribute__((ext_vector_type(4)));

// LDS-only barrier: orders ds ops without draining global loads/stores.
#define BARRIER_LDS() asm volatile("s_waitcnt lgkmcnt(0)\n\ts_barrier" ::: "memory")

// Pin a loaded value against rematerialization.
#define PIN_V2(x) asm volatile("" : "+v"(x))

// DPP quad_perm [1,0,3,2] add: x + x_from(lane^1).  Pure VALU.
__device__ __forceinline__ float dpp_add_x1(float x) {
    int y = __builtin_amdgcn_mov_dpp(__float_as_int(x), 0xB1, 0xF, 0xF, true);
    return x + __int_as_float(y);
}
// DPP quad_perm [2,3,0,1]: fetch value from lane^2 (gate-pair partner).
__device__ __forceinline__ float dpp_get_x2(float x) {
    int y = __builtin_amdgcn_mov_dpp(__float_as_int(x), 0x4E, 0xF, 0xF, true);
    return __int_as_float(y);
}

// ---------------------------------------------------------------------------
// cross-WG sync helpers (device-scope; per-XCD L2s are non-coherent)
// ---------------------------------------------------------------------------
__device__ __forceinline__ void wg_wait_ge(int* flag, int target) {
    if (threadIdx.x == 0) {
        while (__hip_atomic_load(flag, __ATOMIC_RELAXED, __HIP_MEMORY_SCOPE_AGENT) < target)
            __builtin_amdgcn_s_sleep(2);
    }
    __syncthreads();
    __builtin_amdgcn_fence(__ATOMIC_ACQUIRE, "agent");
}
__device__ __forceinline__ void wg_publish(int* a, int va, int* b, int vb) {
    __syncthreads();
    if (threadIdx.x == 0) {
        if (a) __hip_atomic_store(a, va, __ATOMIC_RELEASE, __HIP_MEMORY_SCOPE_AGENT);
        if (b) __hip_atomic_store(b, vb, __ATOMIC_RELEASE, __HIP_MEMORY_SCOPE_AGENT);
    }
}

// ---------------------------------------------------------------------------
__device__ __forceinline__ float sigmoid_(float x) {
    return 1.f / (1.f + __expf(-x));
}
__device__ __forceinline__ float tanh_(float x) {
    float e = __expf(2.f * x);
    return 1.f - 2.f / (e + 1.f);
}

// ---------------------------------------------------------------------------
// GEMM with bias: C[M,N] = A[M,K] @ B[K,N] + bias[N]   (fp32, 64x64 tile)
// Writes PERMUTED columns: col n=(g*100+u) lands at u*4+g (unit-major i,f,g,o).
// ---------------------------------------------------------------------------
__global__ __launch_bounds__(256) void gemm_bias_kernel(
    const float* __restrict__ A, const float* __restrict__ B,
    const float* __restrict__ bias, float* __restrict__ C,
    int M, int N, int K)
{
    __shared__ float As[16][65];
    __shared__ float Bs[16][65];
    const int tid = threadIdx.x;
    const int tx = tid & 15;
    const int ty = tid >> 4;
    const int bm = blockIdx.y * 64;
    const int bn = blockIdx.x * 64;
    float acc[4][4] = {};

    for (int k0 = 0; k0 < K; k0 += 16) {
        #pragma unroll
        for (int p = 0; p < 4; ++p) {
            int e = tid + p * 256;
            int r = e >> 4, cc = e & 15;
            int m = bm + r, k = k0 + cc;
            float v = (m < M && k < K) ? A[(long)m * K + k] : 0.f;
            As[cc][r] = v;
        }
        #pragma unroll
        for (int p = 0; p < 4; ++p) {
            int e = tid + p * 256;
            int r = e >> 6, cc = e & 63;
            int k = k0 + r, n = bn + cc;
            float v = (k < K && n < N) ? B[(long)k * N + n] : 0.f;
            Bs[r][cc] = v;
        }
        __syncthreads();
        #pragma unroll
        for (int kk = 0; kk < 16; ++kk) {
            float a[4], b[4];
            #pragma unroll
            for (int i = 0; i < 4; ++i) a[i] = As[kk][ty * 4 + i];
            #pragma unroll
            for (int j = 0; j < 4; ++j) b[j] = Bs[kk][tx * 4 + j];
            #pragma unroll
            for (int i = 0; i < 4; ++i)
                #pragma unroll
                for (int j = 0; j < 4; ++j)
                    acc[i][j] += a[i] * b[j];
        }
        __syncthreads();
    }
    #pragma unroll
    for (int i = 0; i < 4; ++i) {
        int m = bm + ty * 4 + i;
        if (m >= M) continue;
        #pragma unroll
        for (int j = 0; j < 4; ++j) {
            int n = bn + tx * 4 + j;
            if (n < N) {
                int pn = (n % 100) * 4 + (n / 100);   // unit-major permute
                C[(long)m * N + pn] = acc[i][j] + bias[n];
            }
        }
    }
}

// ---------------------------------------------------------------------------
// Recurrent role (R18: 4-way split, k-pair packed, all-DPP reduce).
// Thread tid = 4u+2gp+s owns gates (2gp, 2gp+1) over k-half s:
// 52 floats x 2 gates = 52 v2f = 104 weight VGPRs -> allocatable (R12 proof).
// Per-wave VALU ~120 instr/step (half of R15's); 8 waves -> 2/SIMD so the
// two waves' chain stalls (ds_read ~120, barrier, transcendentals) overlap
// with each other's issue.  k-pair packing: acc_g += {w[k],w[k+1]} *
// {h[k],h[k+1]} with the h pair taken directly from ds_read_b128 (no splat
// movs).  xor1 (k-halves) and xor2 (gate pairs) via quad_perm DPP.
// Association change vs reference ~ R17's (absmax 2e-3, passed).
// ---------------------------------------------------------------------------
__device__ void rec_role(
    const float* __restrict__ xz, int xz_ring,   // [T][400] or ring, permuted
    const float* __restrict__ U,                 // [100][400] original layout
    float* __restrict__ hout, long h_stride, int h_ring, // transposed [100][h_stride]
    int* flag_up, int* done_self, int* done_down, int* flag_self,
    float* lds)                                   // >= 2*KPAD floats
{
    float* hb0 = lds;            // 104 floats (pad zeros)
    float* hb1 = lds + KPAD;     // 416 B offset, 16B-aligned
    const int tid = threadIdx.x;
    const bool active = tid < 4 * NU;   // 400 workers
    const int u  = tid >> 2;
    const int gp = (tid >> 1) & 1;      // gate pair: 0 -> (i,f), 1 -> (g,o)
    const int s  = tid & 1;             // k-half

    // weights: wa[j] = {U[k][ga*100+u], U[k+1][ga*100+u]}, k = 52s+2j,
    // ga = 2gp (gate a) / 2gp+1 (gate b); zeros for k >= 100.
    v2f wa[KPAIR], wb[KPAIR];
    if (active) {
        const int k0 = KHALF * s;
        const int ga = 2 * gp * NU, gb = (2 * gp + 1) * NU;
        #pragma unroll
        for (int j = 0; j < KPAIR; ++j) {
            int k = k0 + 2 * j;
            float a0 = 0.f, a1 = 0.f, b0 = 0.f, b1 = 0.f;
            if (k < NU)     { a0 = U[(long)k * NG + ga + u];       b0 = U[(long)k * NG + gb + u]; }
            if (k + 1 < NU) { a1 = U[(long)(k + 1) * NG + ga + u]; b1 = U[(long)(k + 1) * NG + gb + u]; }
            wa[j] = (v2f){a0, a1};
            wb[j] = (v2f){b0, b1};
            PIN_V2(wa[j]); PIN_V2(wb[j]);
        }
    }
    if (tid < KPAD) { hb0[tid] = 0.f; hb1[tid] = 0.f; }
    float c_state = 0.f;
    // 4-deep xw register pipeline: xwp0 used this step, xwp3 in flight (t+4)
    float2 xwp0 = make_float2(0.f, 0.f), xwp1 = xwp0, xwp2 = xwp0, xwp3 = xwp0;
    float4 hbatch = make_float4(0.f, 0.f, 0.f, 0.f);

    // incremental addressing (no per-step %RN / 64-bit muls)
    const float* xz_lane = xz + 4 * u + 2 * gp;   // this thread's gate-pair cols
    float* hout_u = hout + (long)u * h_stride;    // per-unit row base
    int nxt  = 4 * NG;                            // element offset of row t+4
    int hoff = 0;                                 // store offset (t-3 wrapped)
    __syncthreads();

    auto step = [&](const float* hrd, float* hwr, int t) {
        if (active) {
            const v4f* h4 = (const v4f*)(hrd + KHALF * s);
            // phase 1: stage all 13 ds_read_b128 (R15)
            v4f hbuf[13];
            #pragma unroll
            for (int q = 0; q < 13; ++q) hbuf[q] = h4[q];
            __builtin_amdgcn_sched_barrier(0);
            // rotate xw pipeline, issue t+4 prefetch (hides under FMAs)
            float2 xw_use = xwp0;
            xwp0 = xwp1; xwp1 = xwp2; xwp2 = xwp3;
            if (t + 4 < T_STEPS) {
                xwp3 = *(const float2*)(xz_lane + nxt);
            }
            nxt += NG;
            if (xz_ring && nxt == RN * NG) nxt = 0;
            __builtin_amdgcn_sched_barrier(0);
            // phase 2: k-pair packed FMAs, 2 independent chains (26 deep)
            v2f a0 = (v2f){0.f, 0.f}, a1 = (v2f){0.f, 0.f};
            #pragma unroll
            for (int q = 0; q < 13; ++q) {
                v2f plo = hbuf[q].xy;             // {h[4q],   h[4q+1]}
                v2f phi = hbuf[q].zw;             // {h[4q+2], h[4q+3]}
                a0 = __builtin_elementwise_fma(wa[2 * q],     plo, a0);
                a1 = __builtin_elementwise_fma(wb[2 * q],     plo, a1);
                a0 = __builtin_elementwise_fma(wa[2 * q + 1], phi, a0);
                a1 = __builtin_elementwise_fma(wb[2 * q + 1], phi, a1);
            }
            float ax = a0.x + a0.y;               // gate 2gp   partial
            float ay = a1.x + a1.y;               // gate 2gp+1 partial
            // fold xw on the lane with s==gp (one fold per gate pair)
            if (s == gp) { ax += xw_use.x; ay += xw_use.y; }
            // sum k-halves (lane^1), then exchange gate pairs (lane^2)
            ax = dpp_add_x1(ax);
            ay = dpp_add_x1(ay);
            float bx2 = dpp_get_x2(ax);
            float by2 = dpp_get_x2(ay);
            // gp=0: (ax,ay)=(i,f), (bx2,by2)=(g,o); gp=1: swapped
            float zi = gp ? bx2 : ax;
            float zf = gp ? by2 : ay;
            float zg = gp ? ax : bx2;
            float zo = gp ? ay : by2;
            float iv = sigmoid_(zi);
            float fv = sigmoid_(zf);
            float gv = tanh_(zg);
            float ov = sigmoid_(zo);
            c_state = fv * c_state + iv * gv;     // replicated per quad
            float h = ov * tanh_(c_state);
            if ((tid & 3) == 0) {
                hwr[u] = h;                       // pad [100..103] stays 0
                // batch 4 steps of h, flush with one dwordx4 (t%4==3)
                int ph = t & 3;
                if      (ph == 0) hbatch.x = h;
                else if (ph == 1) hbatch.y = h;
                else if (ph == 2) hbatch.z = h;
                else {
                    hbatch.w = h;
                    *(float4*)(hout_u + hoff) = hbatch;
                    hoff += 4;
                    if (h_ring && hoff == RN) hoff = 0;
                }
            }
        }
        BARRIER_LDS();
    };

    for (int c = 0; c < NCHUNK; ++c) {
        if (flag_up) {
            int tgt = c + 2; if (tgt > NCHUNK) tgt = NCHUNK;
            wg_wait_ge(flag_up, tgt);
        }
        if (done_down && c >= RING) wg_wait_ge(done_down, c - RING + 1);
        if (c == 0 && active) {
            xwp0 = *(const float2*)(xz_lane);
            xwp1 = *(const float2*)(xz_lane + NG);
            xwp2 = *(const float2*)(xz_lane + 2 * NG);
            xwp3 = *(const float2*)(xz_lane + 3 * NG);
        }
        const int t0 = c * CHUNK;
        for (int tt = 0; tt < CHUNK; tt += 2) {
            step(hb0, hb1, t0 + tt);
            step(hb1, hb0, t0 + tt + 1);
        }
        wg_publish(done_self, c + 1, flag_self, c + 1);   // vmcnt(0) drained inside
    }
}

// ---------------------------------------------------------------------------
// Projection role (R18: same 4-way split / k-pair packing).  Reads TRANSPOSED
// h ring hin[u][RN]; staging loop iterates t-major (coalesced).
// ---------------------------------------------------------------------------
__device__ void proj_role(
    const float* __restrict__ hin,     // transposed ring [100][RN]
    const float* __restrict__ W,       // [100][400] original layout
    const float* __restrict__ bias,    // [400] gate-major index
    const float* __restrict__ g, const float* __restrict__ be,
    const float* __restrict__ m, const float* __restrict__ v,
    float* __restrict__ xzout,         // ring [RN][400] permuted
    int* flag_up, int* done_self, int* done_down, int* flag_self,
    float* lds)                         // CHUNK*KPAD floats (99.8 KB)
{
    const int tid = threadIdx.x;
    const bool active = tid < 4 * NU;
    const int u  = tid >> 2;
    const int gp = (tid >> 1) & 1;
    const int s  = tid & 1;

    v2f wa[KPAIR], wb[KPAIR];
    float bx = 0.f, by = 0.f;
    if (active) {
        const int k0 = KHALF * s;
        const int ga = 2 * gp * NU, gb = (2 * gp + 1) * NU;
        float pba = 0.f, pbb = 0.f;
        #pragma unroll
        for (int j = 0; j < KPAIR; ++j) {
            int k = k0 + 2 * j;
            float a0 = 0.f, a1 = 0.f, b0 = 0.f, b1 = 0.f;
            if (k < NU) {
                float sc = g[k] * rsqrtf(v[k] + 1e-3f);
                float sh = be[k] - m[k] * sc;
                float qa = W[(long)k * NG + ga + u];
                float qb = W[(long)k * NG + gb + u];
                a0 = sc * qa; b0 = sc * qb;
                pba += sh * qa; pbb += sh * qb;
            }
            if (k + 1 < NU) {
                int kk = k + 1;
                float sc = g[kk] * rsqrtf(v[kk] + 1e-3f);
                float sh = be[kk] - m[kk] * sc;
                float qa = W[(long)kk * NG + ga + u];
                float qb = W[(long)kk * NG + gb + u];
                a1 = sc * qa; b1 = sc * qb;
                pba += sh * qa; pbb += sh * qb;
            }
            wa[j] = (v2f){a0, a1};
            wb[j] = (v2f){b0, b1};
            PIN_V2(wa[j]); PIN_V2(wb[j]);
        }
        pba += __shfl_xor(pba, 1); pbb += __shfl_xor(pbb, 1);
        bx = bias[ga + u] + pba;
        by = bias[gb + u] + pbb;
    }

    for (int c = 0; c < NCHUNK; ++c) {
        wg_wait_ge(flag_up, c + 1);
        if (c >= RING) wg_wait_ge(done_down, c - RING + 1);
        // stage h chunk into LDS[r][k] (row stride KPAD, zeros in pad).
        {
            const int tbase = (c % RING) * CHUNK;   // == t0 % RN
            for (int idx = tid; idx < KPAD * CHUNK; idx += BLK) {
                int k = idx / CHUNK, r = idx - k * CHUNK;
                lds[r * KPAD + k] = (k < NU) ? hin[(long)k * RN + tbase + r] : 0.f;
            }
        }
        wg_publish(done_self, c + 1, (int*)0, 0);
        if (active) {
            float* ob = xzout + (size_t)(c % RING) * CHUNK * NG;
            for (int r = 0; r < CHUNK; ++r) {
                const v4f* h4 = (const v4f*)(lds + r * KPAD + KHALF * s);
                v2f a0 = (v2f){0.f, 0.f}, a1 = (v2f){0.f, 0.f};
                #pragma unroll
                for (int q = 0; q < 13; ++q) {
                    v4f hv = h4[q];
                    v2f plo = hv.xy;
                    v2f phi = hv.zw;
                    a0 = __builtin_elementwise_fma(wa[2 * q],     plo, a0);
                    a1 = __builtin_elementwise_fma(wb[2 * q],     plo, a1);
                    a0 = __builtin_elementwise_fma(wa[2 * q + 1], phi, a0);
                    a1 = __builtin_elementwise_fma(wb[2 * q + 1], phi, a1);
                }
                float ax = a0.x + a0.y;
                float ay = a1.x + a1.y;
                ax = dpp_add_x1(ax);     // sum k-halves
                ay = dpp_add_x1(ay);
                if (s == 0)
                    *(float2*)&ob[(long)r * NG + 4 * u + 2 * gp]
                        = make_float2(ax + bx, ay + by);
            }
        }
        wg_publish(flag_self, c + 1, (int*)0, 0);
    }
}

// ---------------------------------------------------------------------------
// Persistent pipeline: block 0..4 = rec1, proj2, rec2, proj3, rec3.
// 512 threads / 8 waves = 2 waves per SIMD: the second wave's issue fills
// the first wave's stall bubbles.  waves_per_eu(2,2) -> 256-VGPR budget per
// wave, enough for the 104-VGPR weight block + working set without spills.
// ---------------------------------------------------------------------------
__global__ __launch_bounds__(BLK)
__attribute__((amdgpu_waves_per_eu(2, 2)))
void lstm_pipe_kernel(
    const float* xw1, const float* U1,
    const float* U2, const float* W2, const float* b2,
    const float* U3, const float* W3, const float* b3,
    const float* g1, const float* be1, const float* m1, const float* v1,
    const float* g2, const float* be2, const float* m2, const float* v2,
    float* h1r, float* h2r, float* xz2r, float* xz3r, float* h3,
    int* f)
{
    extern __shared__ float smem[];
    int* f_h1  = f +   0;
    int* d_p2  = f +  32;
    int* f_xz2 = f +  64;
    int* d_r2  = f +  96;
    int* f_h2  = f + 128;
    int* d_p3  = f + 160;
    int* f_xz3 = f + 192;
    int* d_r3  = f + 224;

    switch (blockIdx.x) {
    case 0: rec_role(xw1, 0, U1, h1r, RN, 1, (int*)0, (int*)0, d_p2, f_h1, smem); break;
    case 1: proj_role(h1r, W2, b2, g1, be1, m1, v1, xz2r, f_h1, d_p2, d_r2, f_xz2, smem); break;
    case 2: rec_role(xz2r, 1, U2, h2r, RN, 1, f_xz2, d_r2, d_p3, f_h2, smem); break;
    case 3: proj_role(h2r, W3, b3, g2, be2, m2, v2, xz3r, f_h2, d_p3, d_r3, f_xz3, smem); break;
    case 4: rec_role(xz3r, 1, U3, h3, T_STEPS, 0, f_xz3, d_r3, (int*)0, (int*)0, smem); break;
    }
}

// ---------------------------------------------------------------------------
// Dense (100->3) + softmax, BN3 folded.  H is TRANSPOSED [100][T] -> the
// per-k read h[k*T+row] is perfectly coalesced across threads (rows).
// ---------------------------------------------------------------------------
__global__ __launch_bounds__(256) void dense_softmax_kernel(
    const float* __restrict__ H,    // [100][T] raw h3 (transposed)
    const float* __restrict__ Wd,
    const float* __restrict__ bd,
    const float* __restrict__ g3, const float* __restrict__ be3,
    const float* __restrict__ m3, const float* __restrict__ v3,
    float* __restrict__ out, int T)
{
    __shared__ float w[300];
    __shared__ float b[3];
    const int tid = threadIdx.x;
    for (int i = tid; i < 300; i += 256) {
        int k = i / 3;
        float sc = g3[k] * rsqrtf(v3[k] + 1e-3f);
        w[i] = Wd[i] * sc;
    }
    if (tid < 3) {
        float acc = bd[tid];
        for (int k = 0; k < NU; ++k) {
            float sc = g3[k] * rsqrtf(v3[k] + 1e-3f);
            float sh = be3[k] - m3[k] * sc;
            acc += sh * Wd[3 * k + tid];
        }
        b[tid] = acc;
    }
    __syncthreads();

    int row = blockIdx.x * blockDim.x + tid;
    if (row >= T) return;
    float s0 = b[0], s1 = b[1], s2 = b[2];
    #pragma unroll 4
    for (int k = 0; k < NU; ++k) {
        float hv = H[(long)k * T + row];
        s0 += hv * w[3 * k + 0];
        s1 += hv * w[3 * k + 1];
        s2 += hv * w[3 * k + 2];
    }
    float mx = fmaxf(s0, fmaxf(s1, s2));
    float e0 = __expf(s0 - mx), e1 = __expf(s1 - mx), e2 = __expf(s2 - mx);
    float inv = 1.f / (e0 + e1 + e2);
    out[(long)row * 3 + 0] = e0 * inv;
    out[(long)row * 3 + 1] = e1 * inv;
    out[(long)row * 3 + 2] = e2 * inv;
}

// ---------------------------------------------------------------------------
extern "C" void kernel_launch(void* const* d_in, const int* in_sizes, int n_in,
                              void* d_out, int out_size, void* d_ws, size_t ws_size,
                              hipStream_t stream)
{
    const float* x   = (const float*)d_in[0];
    const float* W1  = (const float*)d_in[1];
    const float* U1  = (const float*)d_in[2];
    const float* b1  = (const float*)d_in[3];
    const float* ga1 = (const float*)d_in[4];
    const float* be1 = (const float*)d_in[5];
    const float* mu1 = (const float*)d_in[6];
    const float* va1 = (const float*)d_in[7];
    const float* W2  = (const float*)d_in[8];
    const float* U2  = (const float*)d_in[9];
    const float* b2  = (const float*)d_in[10];
    const float* ga2 = (const float*)d_in[11];
    const float* be2 = (const float*)d_in[12];
    const float* mu2 = (const float*)d_in[13];
    const float* va2 = (const float*)d_in[14];
    const float* W3  = (const float*)d_in[15];
    const float* U3  = (const float*)d_in[16];
    const float* b3  = (const float*)d_in[17];
    const float* ga3 = (const float*)d_in[18];
    const float* be3 = (const float*)d_in[19];
    const float* mu3 = (const float*)d_in[20];
    const float* va3 = (const float*)d_in[21];
    const float* Wd  = (const float*)d_in[22];
    const float* bd  = (const float*)d_in[23];

    // workspace layout (floats) — total ~51.9 MB
    float* xw1  = (float*)d_ws;                       // T*400 (permuted)
    float* h3   = xw1  + (size_t)T_STEPS * NG;        // [100][T] transposed
    float* h1r  = h3   + (size_t)T_STEPS * NU;        // [100][RN] transposed ring
    float* h2r  = h1r  + (size_t)RN * NU;
    float* xz2r = h2r  + (size_t)RN * NU;             // RN*400 (permuted)
    float* xz3r = xz2r + (size_t)RN * NG;
    int*   flags = (int*)(xz3r + (size_t)RN * NG);    // 512 ints
    float* out = (float*)d_out;

    dim3 blk(256);
    dim3 grd((NG + 63) / 64, (T_STEPS + 63) / 64);

    // 1) input projection of layer 1 (permuted-column output)
    gemm_bias_kernel<<<grd, blk, 0, stream>>>(x, W1, b1, xw1, T_STEPS, NG, DIN);
    // 2) zero the pipeline flags
    hipMemsetAsync(flags, 0, 512 * sizeof(int), stream);
    // 3) persistent pipeline: 5 blocks x 512 threads, 99.8 KB dynamic LDS
    lstm_pipe_kernel<<<5, BLK, CHUNK * KPAD * sizeof(float), stream>>>(
        xw1, U1, U2, W2, b2, U3, W3, b3,
        ga1, be1, mu1, va1, ga2, be2, mu2, va2,
        h1r, h2r, xz2r, xz3r, h3, flags);
    // 4) dense + softmax (BN3 folded, transposed-H reads)
    dense_softmax_kernel<<<(T_STEPS + 255) / 256, 256, 0, stream>>>(
        h3, Wd, bd, ga3, be3, mu3, va3, out, T_STEPS);
}